// Round 11
// baseline (165.975 us; speedup 1.0000x reference)
//
#include <hip/hip_runtime.h>

#define NDIM 2
#define NCELLS 200
#define BATCH 128
#define NPTS (BATCH * NCELLS)      /* 25600 */
#define NBLK (NPTS / 32)           /* 800 waves, 2 chains x 16 points */
#define XROW (2 + NCELLS * NDIM + 5) /* 407 */
#define DT_F 0.001f
#define LOG2E 1.4426950408889634f
#define LN2   0.6931471805599453f

typedef _Float16 v4h __attribute__((ext_vector_type(4)));
typedef _Float16 h2  __attribute__((ext_vector_type(2)));
typedef float    v4f __attribute__((ext_vector_type(4)));

#define MFMA16(A, B, C) __builtin_amdgcn_mfma_f32_16x16x16f16((A), (B), (C), 0, 0, 0)
// Zero-cost cross-chain tie: forces chain A's next stage to depend on chain
// B's current stage (and vice versa) so the scheduler CANNOT serialize the
// two chains (r7 lesson: left free, it sank chain B wholesale -> VGPR 76,
// no ILP, 1.13x regression).
#define TIE(a, b) asm volatile("" : "+v"(a), "+v"(b))

__device__ __forceinline__ v4h pk4(const v4f v) {
    h2 lo = __builtin_bit_cast(h2, __builtin_amdgcn_cvt_pkrtz(v[0], v[1]));
    h2 hi = __builtin_bit_cast(h2, __builtin_amdgcn_cvt_pkrtz(v[2], v[3]));
    return __builtin_shufflevector(lo, hi, 0, 1, 2, 3);
}

// Raw-instruction softplus/sigmoid (r9 lesson: __expf/__logf lowered to
// multi-inst libm -> issue-bound). e=exp2(-|z|log2e); a=max(z,0)+log2(1+e)ln2;
// s=(z>=0?1:e)*rcp(1+e).
__device__ __forceinline__ void act4(const v4f z, v4h& ah, v4h& qh) {
    v4f a, s;
    #pragma unroll
    for (int i = 0; i < 4; ++i) {
        float e = __builtin_amdgcn_exp2f(-fabsf(z[i]) * LOG2E);
        float t = 1.0f + e;
        float L = __builtin_amdgcn_logf(t);          // log2(t)
        float r = __builtin_amdgcn_rcpf(t);
        a[i] = fmaf(L, LN2, fmaxf(z[i], 0.0f));
        s[i] = (z[i] >= 0.0f) ? r : e * r;
    }
    ah = pk4(a);
    qh = pk4(s);
}

__device__ __forceinline__ v4h sig4(const v4f z) {
    v4f s;
    #pragma unroll
    for (int i = 0; i < 4; ++i) {
        float e = __builtin_amdgcn_exp2f(-fabsf(z[i]) * LOG2E);
        float r = __builtin_amdgcn_rcpf(1.0f + e);
        s[i] = (z[i] >= 0.0f) ? r : e * r;
    }
    return pk4(s);
}

// MFMA 16x16x16 f16 layouts (m89-verified family):
//   A[m][k]: m=lane&15, k=(lane>>4)*4+i ; B[k][n]: n=lane&15, k=(lane>>4)*4+i
//   C/D[m][n]: n=lane&15, m=(lane>>4)*4+reg
// D of one layer == B-layout of the next -> no cross-lane movement, no LDS.

__global__ void __launch_bounds__(64, 1) phinn_kernel(
    const float* __restrict__ w0, const float* __restrict__ b0,
    const float* __restrict__ w1, const float* __restrict__ b1,
    const float* __restrict__ w2, const float* __restrict__ b2,
    const float* __restrict__ w3, const float* __restrict__ b3,
    const float* __restrict__ w4, const float* __restrict__ b4,
    const float* __restrict__ wt, const float* __restrict__ x,
    float* __restrict__ out)
{
    const int lane = threadIdx.x;     // 1 wave per block
    const int g = lane >> 4;          // k-group 0..3
    const int m = lane & 15;          // row (A) / col (B,C/D) index

    // ---------- one-time weight fragment preload (registers, f16) ----------
    v4h fW0, fW0T, fW1[2], fW1T[2], fW2[2][2], fW2T[2][2], fW3[2], fW3T[2];
    #pragma unroll
    for (int i = 0; i < 4; ++i) {
        const int k = 4 * g + i;
        fW0[i] = (k < 2) ? (_Float16)w0[m * 2 + k] : (_Float16)0.f;
        #pragma unroll
        for (int t = 0; t < 2; ++t) {
            fW1[t][i]  = (_Float16)w1[(16 * t + m) * 16 + k];
            fW3[t][i]  = (_Float16)w3[m * 32 + 16 * t + k];
            fW1T[t][i] = (_Float16)w1[(16 * t + k) * 16 + m];
            fW3T[t][i] = (_Float16)w3[k * 32 + 16 * t + m];
            #pragma unroll
            for (int u = 0; u < 2; ++u) {
                fW2[t][u][i]  = (_Float16)w2[(16 * t + m) * 32 + 16 * u + k];
                fW2T[t][u][i] = (_Float16)w2[(16 * u + k) * 32 + 16 * t + m];
            }
        }
        fW0T[i] = (m < 2) ? (_Float16)w0[k * 2 + m] : (_Float16)0.f;
    }
    v4f b0a, b1a0, b1a1, b2a0, b2a1, b3a;
    v4h w4h;
    #pragma unroll
    for (int r = 0; r < 4; ++r) {
        b0a[r]  = b0[4 * g + r];
        b1a0[r] = b1[4 * g + r];   b1a1[r] = b1[16 + 4 * g + r];
        b2a0[r] = b2[4 * g + r];   b2a1[r] = b2[16 + 4 * g + r];
        b3a[r]  = b3[4 * g + r];
        w4h[r]  = (_Float16)w4[4 * g + r];
    }
    const float wt00 = wt[0], wt01 = wt[1], wt10 = wt[2], wt11 = wt[3];

    // ---------- per-chain state (2 chains: points p, p+16) ----------
    float y0c[2], y1c[2], tsc[2], sp0c[2];
    float tl0c[2], tl1c[2], th0c[2], th1c[2];
    int pc[2];
    #pragma unroll
    for (int c = 0; c < 2; ++c) {
        const int p = blockIdx.x * 32 + 16 * c + m;
        pc[c] = p;
        const int bi = p / NCELLS;
        const int ci = p - bi * NCELLS;
        const float* xr = x + bi * XROW;
        y0c[c] = xr[2 + 2 * ci];
        y1c[c] = xr[3 + 2 * ci];
        tsc[c] = xr[0];
        sp0c[c] = xr[XROW - 5];
        const float sg_lo0 = xr[XROW - 4], sg_lo1 = xr[XROW - 3];
        const float sg_hi0 = xr[XROW - 2], sg_hi1 = xr[XROW - 1];
        tl0c[c] = sg_lo0 * wt00 + sg_lo1 * wt01;
        tl1c[c] = sg_lo0 * wt10 + sg_lo1 * wt11;
        th0c[c] = sg_hi0 * wt00 + sg_hi1 * wt01;
        th1c[c] = sg_hi0 * wt10 + sg_hi1 * wt11;
    }

    const int nsteps = (int)((x[1] - x[0]) / DT_F + 0.5f);
    const v4f zf = {0.f, 0.f, 0.f, 0.f};
    const h2 zero2 = {(_Float16)0.f, (_Float16)0.f};

    // fY: all lanes hold (y0,y1,0,0). Lanes g!=0 feed B-rows k>=4 whose
    // A-columns are exactly zero (fW0[i]=0 for k>=2) -> finite garbage * 0.
    // Saves the per-step per-lane cndmasks of r6-r10.
    v4h fY[2];
    #pragma unroll
    for (int c = 0; c < 2; ++c) {
        h2 ylo = __builtin_bit_cast(h2, __builtin_amdgcn_cvt_pkrtz(y0c[c], y1c[c]));
        fY[c] = __builtin_shufflevector(ylo, zero2, 0, 1, 2, 3);
    }

    #pragma unroll 1
    for (int it = 0; it < nsteps; ++it) {
        // ---- L1 ----
        v4f z1[2];
        z1[0] = MFMA16(fW0, fY[0], b0a);
        z1[1] = MFMA16(fW0, fY[1], b0a);
        TIE(z1[0], z1[1]);
        v4h a1h[2], q1h[2];
        act4(z1[0], a1h[0], q1h[0]);
        act4(z1[1], a1h[1], q1h[1]);
        TIE(a1h[0], a1h[1]);
        // ---- L2 ----
        v4f z20[2], z21[2];
        z20[0] = MFMA16(fW1[0], a1h[0], b1a0);
        z20[1] = MFMA16(fW1[0], a1h[1], b1a0);
        z21[0] = MFMA16(fW1[1], a1h[0], b1a1);
        z21[1] = MFMA16(fW1[1], a1h[1], b1a1);
        TIE(z20[0], z20[1]);
        TIE(z21[0], z21[1]);
        v4h a2h0[2], a2h1[2], q2h0[2], q2h1[2];
        act4(z20[0], a2h0[0], q2h0[0]);
        act4(z20[1], a2h0[1], q2h0[1]);
        act4(z21[0], a2h1[0], q2h1[0]);
        act4(z21[1], a2h1[1], q2h1[1]);
        TIE(a2h0[0], a2h0[1]);
        TIE(a2h1[0], a2h1[1]);
        // ---- L3 ----
        v4f z30[2], z31[2];
        #pragma unroll
        for (int c = 0; c < 2; ++c) {
            v4f acc0 = MFMA16(fW2[0][0], a2h0[c], b2a0);
            z30[c] = MFMA16(fW2[0][1], a2h1[c], acc0);
            v4f acc1 = MFMA16(fW2[1][0], a2h0[c], b2a1);
            z31[c] = MFMA16(fW2[1][1], a2h1[c], acc1);
        }
        TIE(z30[0], z30[1]);
        TIE(z31[0], z31[1]);
        v4h a3h0[2], a3h1[2], q3h0[2], q3h1[2];
        act4(z30[0], a3h0[0], q3h0[0]);
        act4(z30[1], a3h0[1], q3h0[1]);
        act4(z31[0], a3h1[0], q3h1[0]);
        act4(z31[1], a3h1[1], q3h1[1]);
        TIE(a3h0[0], a3h0[1]);
        TIE(a3h1[0], a3h1[1]);
        // ---- L4 + g4 ----
        v4f z4[2];
        #pragma unroll
        for (int c = 0; c < 2; ++c) {
            v4f acc = MFMA16(fW3[0], a3h0[c], b3a);
            z4[c] = MFMA16(fW3[1], a3h1[c], acc);
        }
        TIE(z4[0], z4[1]);
        v4h g4h[2];
        g4h[0] = sig4(z4[0]) * w4h;
        g4h[1] = sig4(z4[1]) * w4h;
        TIE(g4h[0], g4h[1]);
        // ---- g3 ----
        v4f s0[2], s1[2];
        #pragma unroll
        for (int c = 0; c < 2; ++c) {
            s0[c] = MFMA16(fW3T[0], g4h[c], zf);
            s1[c] = MFMA16(fW3T[1], g4h[c], zf);
        }
        TIE(s0[0], s0[1]);
        TIE(s1[0], s1[1]);
        v4h g3h0[2], g3h1[2];
        #pragma unroll
        for (int c = 0; c < 2; ++c) {
            g3h0[c] = pk4(s0[c]) * q3h0[c];
            g3h1[c] = pk4(s1[c]) * q3h1[c];
        }
        TIE(g3h0[0], g3h0[1]);
        TIE(g3h1[0], g3h1[1]);
        // ---- g2 ----
        v4f u0[2], u1[2];
        #pragma unroll
        for (int c = 0; c < 2; ++c) {
            v4f a = MFMA16(fW2T[0][0], g3h0[c], zf);
            u0[c] = MFMA16(fW2T[0][1], g3h1[c], a);
            v4f b = MFMA16(fW2T[1][0], g3h0[c], zf);
            u1[c] = MFMA16(fW2T[1][1], g3h1[c], b);
        }
        TIE(u0[0], u0[1]);
        TIE(u1[0], u1[1]);
        v4h g2h0[2], g2h1[2];
        #pragma unroll
        for (int c = 0; c < 2; ++c) {
            g2h0[c] = pk4(u0[c]) * q2h0[c];
            g2h1[c] = pk4(u1[c]) * q2h1[c];
        }
        TIE(g2h0[0], g2h0[1]);
        TIE(g2h1[0], g2h1[1]);
        // ---- g1 + gy + update ----
        v4f w[2];
        #pragma unroll
        for (int c = 0; c < 2; ++c) {
            v4f a = MFMA16(fW1T[0], g2h0[c], zf);
            w[c] = MFMA16(fW1T[1], g2h1[c], a);
        }
        TIE(w[0], w[1]);
        v4h g1h[2];
        #pragma unroll
        for (int c = 0; c < 2; ++c)
            g1h[c] = pk4(w[c]) * q1h[c];
        TIE(g1h[0], g1h[1]);
        v4f gy[2];
        gy[0] = MFMA16(fW0T, g1h[0], zf);
        gy[1] = MFMA16(fW0T, g1h[1], zf);
        TIE(gy[0], gy[1]);
        #pragma unroll
        for (int c = 0; c < 2; ++c) {
            const bool lo = tsc[c] < sp0c[c];
            const float tilt0 = lo ? tl0c[c] : th0c[c];
            const float tilt1 = lo ? tl1c[c] : th1c[c];
            y0c[c] = fmaf(-(gy[c][0] + tilt0), DT_F, y0c[c]);
            y1c[c] = fmaf(-(gy[c][1] + tilt1), DT_F, y1c[c]);
            tsc[c] += DT_F;
            h2 ylo = __builtin_bit_cast(h2, __builtin_amdgcn_cvt_pkrtz(y0c[c], y1c[c]));
            fY[c] = __builtin_shufflevector(ylo, zero2, 0, 1, 2, 3);
        }
    }

    if (g == 0) {
        #pragma unroll
        for (int c = 0; c < 2; ++c) {
            out[2 * pc[c] + 0] = y0c[c];
            out[2 * pc[c] + 1] = y1c[c];
        }
    }
}

extern "C" void kernel_launch(void* const* d_in, const int* in_sizes, int n_in,
                              void* d_out, int out_size, void* d_ws, size_t ws_size,
                              hipStream_t stream) {
    (void)in_sizes; (void)n_in; (void)d_ws; (void)ws_size; (void)out_size;
    const float* w0 = (const float*)d_in[0];
    const float* b0 = (const float*)d_in[1];
    const float* w1 = (const float*)d_in[2];
    const float* b1 = (const float*)d_in[3];
    const float* w2 = (const float*)d_in[4];
    const float* b2 = (const float*)d_in[5];
    const float* w3 = (const float*)d_in[6];
    const float* b3 = (const float*)d_in[7];
    const float* w4 = (const float*)d_in[8];
    const float* b4 = (const float*)d_in[9];
    const float* wt = (const float*)d_in[10];
    const float* x  = (const float*)d_in[11];
    float* out = (float*)d_out;

    dim3 grid(NBLK), block(64);
    hipLaunchKernelGGL(phinn_kernel, grid, block, 0, stream,
                       w0, b0, w1, b1, w2, b2, w3, b3, w4, b4, wt, x, out);
}

// Round 12
// 155.922 us; speedup vs baseline: 1.0645x; 1.0645x over previous
//
#include <hip/hip_runtime.h>

#define NDIM 2
#define NCELLS 200
#define BATCH 128
#define NPTS (BATCH * NCELLS)      /* 25600 */
#define NBLK (NPTS / 16)           /* 1600 waves, 16 points each */
#define XROW (2 + NCELLS * NDIM + 5) /* 407 */
#define DT_F 0.001f
#define LOG2E 1.4426950408889634f

typedef _Float16 v4h __attribute__((ext_vector_type(4)));
typedef _Float16 h2  __attribute__((ext_vector_type(2)));
typedef float    v4f __attribute__((ext_vector_type(4)));

#define MFMA16(A, B, C) __builtin_amdgcn_mfma_f32_16x16x16f16((A), (B), (C), 0, 0, 0)

__device__ __forceinline__ h2 pkh(float a, float b) {
    return __builtin_bit_cast(h2, __builtin_amdgcn_cvt_pkrtz(a, b));
}
__device__ __forceinline__ h2 h2c(float v) {
    _Float16 h = (_Float16)v; h2 r; r[0] = h; r[1] = h; return r;
}
__device__ __forceinline__ v4h pk4(const v4f v) {
    h2 lo = pkh(v[0], v[1]);
    h2 hi = pkh(v[2], v[3]);
    return __builtin_shufflevector(lo, hi, 0, 1, 2, 3);
}

// r11 lesson (cycle accounting): v_exp/v_log/v_rcp issue at ~16 cyc (wave64
// quarter-rate) and were ~63% of all issue. Keep ONLY the exp; do log and
// rcp with packed-f16 FMA algebra:
//   e  = exp2(-|z|*log2e)                                  (f32, 1 trans)
//   ln(1+e) = deg-6 Taylor about e=0.5   (|err|<7e-5)      (6 pk_fma)
//   sigma+ = 1/(1+e) = linear seed + 2 Newton (f16-exact)  (5 pk ops)
//   sigma  = 0.5 + copysign(sigma+ - 0.5, z)               (2 bit ops, no cmp)
//   softplus = (z+|z|)/2 + ln(1+e)
__device__ __forceinline__ void act_pair(float z0, float z1, h2& ah, h2& qh) {
    float e0f = __builtin_amdgcn_exp2f(-fabsf(z0) * LOG2E);
    float e1f = __builtin_amdgcn_exp2f(-fabsf(z1) * LOG2E);
    h2 zh = pkh(z0, z1);
    h2 eh = pkh(e0f, e1f);
    h2 w = eh - h2c(0.5f);
    h2 L = h2c(-0.01463192f);
    L = L * w + h2c( 0.02633745f);
    L = L * w + h2c(-0.04938272f);
    L = L * w + h2c( 0.09876543f);
    L = L * w + h2c(-0.22222222f);
    L = L * w + h2c( 0.66666667f);
    L = L * w + h2c( 0.40546511f);
    h2 zabs = __builtin_bit_cast(h2, __builtin_bit_cast(unsigned, zh) & 0x7FFF7FFFu);
    ah = (zh + zabs) * h2c(0.5f) + L;
    h2 d = eh + h2c(1.0f);
    h2 r = eh * h2c(-0.5f) + h2c(0.9571f);
    r = r * (h2c(2.0f) - d * r);
    r = r * (h2c(2.0f) - d * r);
    h2 v = r - h2c(0.5f);
    unsigned sgn = __builtin_bit_cast(unsigned, zh) & 0x80008000u;
    qh = __builtin_bit_cast(h2, __builtin_bit_cast(unsigned, v) | sgn) + h2c(0.5f);
}

__device__ __forceinline__ h2 sig_pair(float z0, float z1) {
    float e0f = __builtin_amdgcn_exp2f(-fabsf(z0) * LOG2E);
    float e1f = __builtin_amdgcn_exp2f(-fabsf(z1) * LOG2E);
    h2 zh = pkh(z0, z1);
    h2 eh = pkh(e0f, e1f);
    h2 d = eh + h2c(1.0f);
    h2 r = eh * h2c(-0.5f) + h2c(0.9571f);
    r = r * (h2c(2.0f) - d * r);
    r = r * (h2c(2.0f) - d * r);
    h2 v = r - h2c(0.5f);
    unsigned sgn = __builtin_bit_cast(unsigned, zh) & 0x80008000u;
    return __builtin_bit_cast(h2, __builtin_bit_cast(unsigned, v) | sgn) + h2c(0.5f);
}

__device__ __forceinline__ void act4(const v4f z, v4h& ah, v4h& qh) {
    h2 aLo, qLo, aHi, qHi;
    act_pair(z[0], z[1], aLo, qLo);
    act_pair(z[2], z[3], aHi, qHi);
    ah = __builtin_shufflevector(aLo, aHi, 0, 1, 2, 3);
    qh = __builtin_shufflevector(qLo, qHi, 0, 1, 2, 3);
}
__device__ __forceinline__ v4h sig4(const v4f z) {
    h2 lo = sig_pair(z[0], z[1]);
    h2 hi = sig_pair(z[2], z[3]);
    return __builtin_shufflevector(lo, hi, 0, 1, 2, 3);
}

// MFMA 16x16x16 f16 layouts (m89-verified family):
//   A[m][k]: m=lane&15, k=(lane>>4)*4+i ; B[k][n]: n=lane&15, k=(lane>>4)*4+i
//   C/D[m][n]: n=lane&15, m=(lane>>4)*4+reg
// D of one layer == B-layout of the next -> no cross-lane movement, no LDS.
// Config: 16 pts/wave, 1600 waves (r7/r11: multi-chain waves lose).

__global__ void __launch_bounds__(64, 1) phinn_kernel(
    const float* __restrict__ w0, const float* __restrict__ b0,
    const float* __restrict__ w1, const float* __restrict__ b1,
    const float* __restrict__ w2, const float* __restrict__ b2,
    const float* __restrict__ w3, const float* __restrict__ b3,
    const float* __restrict__ w4, const float* __restrict__ b4,
    const float* __restrict__ wt, const float* __restrict__ x,
    float* __restrict__ out)
{
    const int lane = threadIdx.x;     // 1 wave per block
    const int g = lane >> 4;          // k-group 0..3
    const int m = lane & 15;          // row (A) / col (B,C/D) index
    const int p = blockIdx.x * 16 + m;

    // ---------- one-time weight fragment preload (registers, f16) ----------
    v4h fW0, fW0T, fW1[2], fW1T[2], fW2[2][2], fW2T[2][2], fW3[2], fW3T[2];
    #pragma unroll
    for (int i = 0; i < 4; ++i) {
        const int k = 4 * g + i;
        fW0[i] = (k < 2) ? (_Float16)w0[m * 2 + k] : (_Float16)0.f;
        #pragma unroll
        for (int t = 0; t < 2; ++t) {
            fW1[t][i]  = (_Float16)w1[(16 * t + m) * 16 + k];
            fW3[t][i]  = (_Float16)w3[m * 32 + 16 * t + k];
            fW1T[t][i] = (_Float16)w1[(16 * t + k) * 16 + m];
            fW3T[t][i] = (_Float16)w3[k * 32 + 16 * t + m];
            #pragma unroll
            for (int u = 0; u < 2; ++u) {
                fW2[t][u][i]  = (_Float16)w2[(16 * t + m) * 32 + 16 * u + k];
                fW2T[t][u][i] = (_Float16)w2[(16 * u + k) * 32 + 16 * t + m];
            }
        }
        fW0T[i] = (m < 2) ? (_Float16)w0[k * 2 + m] : (_Float16)0.f;
    }
    v4f b0a, b1a0, b1a1, b2a0, b2a1, b3a;
    v4h w4h;
    #pragma unroll
    for (int r = 0; r < 4; ++r) {
        b0a[r]  = b0[4 * g + r];
        b1a0[r] = b1[4 * g + r];   b1a1[r] = b1[16 + 4 * g + r];
        b2a0[r] = b2[4 * g + r];   b2a1[r] = b2[16 + 4 * g + r];
        b3a[r]  = b3[4 * g + r];
        w4h[r]  = (_Float16)w4[4 * g + r];
    }
    const float wt00 = wt[0], wt01 = wt[1], wt10 = wt[2], wt11 = wt[3];

    // ---------- per-point state ----------
    const int bi = p / NCELLS;
    const int ci = p - bi * NCELLS;
    const float* xr = x + bi * XROW;
    float y0 = xr[2 + 2 * ci];
    float y1 = xr[3 + 2 * ci];
    float ts = xr[0];
    const float sp0    = xr[XROW - 5];
    const float sg_lo0 = xr[XROW - 4], sg_lo1 = xr[XROW - 3];
    const float sg_hi0 = xr[XROW - 2], sg_hi1 = xr[XROW - 1];
    const float tl0 = sg_lo0 * wt00 + sg_lo1 * wt01;
    const float tl1 = sg_lo0 * wt10 + sg_lo1 * wt11;
    const float th0 = sg_hi0 * wt00 + sg_hi1 * wt01;
    const float th1 = sg_hi0 * wt10 + sg_hi1 * wt11;

    const int nsteps = (int)((x[1] - x[0]) / DT_F + 0.5f);
    const v4f zf = {0.f, 0.f, 0.f, 0.f};
    const h2 zero2 = {(_Float16)0.f, (_Float16)0.f};

    // All lanes hold (y0,y1,0,0); lanes g!=0 feed B-rows k>=4 whose A-cols
    // are exactly zero (fW0[i]=0 for k>=2) -> garbage * 0 (r11-verified).
    v4h fY = __builtin_shufflevector(pkh(y0, y1), zero2, 0, 1, 2, 3);

    #pragma unroll 1
    for (int it = 0; it < nsteps; ++it) {
        // ---- forward ----
        v4f z1 = MFMA16(fW0, fY, b0a);
        v4h a1h, q1h; act4(z1, a1h, q1h);

        v4f z20 = MFMA16(fW1[0], a1h, b1a0);
        v4f z21 = MFMA16(fW1[1], a1h, b1a1);
        v4h a2h0, q2h0; act4(z20, a2h0, q2h0);
        v4h a2h1, q2h1; act4(z21, a2h1, q2h1);

        v4f z30 = MFMA16(fW2[0][0], a2h0, b2a0);
        z30 = MFMA16(fW2[0][1], a2h1, z30);
        v4f z31 = MFMA16(fW2[1][0], a2h0, b2a1);
        z31 = MFMA16(fW2[1][1], a2h1, z31);
        v4h a3h0, q3h0; act4(z30, a3h0, q3h0);
        v4h a3h1, q3h1; act4(z31, a3h1, q3h1);

        v4f z4 = MFMA16(fW3[0], a3h0, b3a);
        z4 = MFMA16(fW3[1], a3h1, z4);

        // ---- backward (sigma multiplies packed f16) ----
        v4h g4h = sig4(z4) * w4h;

        v4f s0 = MFMA16(fW3T[0], g4h, zf);
        v4f s1 = MFMA16(fW3T[1], g4h, zf);
        v4h g3h0 = pk4(s0) * q3h0;
        v4h g3h1 = pk4(s1) * q3h1;

        v4f u0 = MFMA16(fW2T[0][0], g3h0, zf);
        u0 = MFMA16(fW2T[0][1], g3h1, u0);
        v4f u1 = MFMA16(fW2T[1][0], g3h0, zf);
        u1 = MFMA16(fW2T[1][1], g3h1, u1);
        v4h g2h0 = pk4(u0) * q2h0;
        v4h g2h1 = pk4(u1) * q2h1;

        v4f w = MFMA16(fW1T[0], g2h0, zf);
        w = MFMA16(fW1T[1], g2h1, w);
        v4h g1h = pk4(w) * q1h;

        v4f gy = MFMA16(fW0T, g1h, zf);

        const bool lo = ts < sp0;
        const float tilt0 = lo ? tl0 : th0;
        const float tilt1 = lo ? tl1 : th1;
        y0 = fmaf(-(gy[0] + tilt0), DT_F, y0);
        y1 = fmaf(-(gy[1] + tilt1), DT_F, y1);
        ts += DT_F;

        fY = __builtin_shufflevector(pkh(y0, y1), zero2, 0, 1, 2, 3);
    }

    if (g == 0) {
        out[2 * p + 0] = y0;
        out[2 * p + 1] = y1;
    }
}

extern "C" void kernel_launch(void* const* d_in, const int* in_sizes, int n_in,
                              void* d_out, int out_size, void* d_ws, size_t ws_size,
                              hipStream_t stream) {
    (void)in_sizes; (void)n_in; (void)d_ws; (void)ws_size; (void)out_size;
    const float* w0 = (const float*)d_in[0];
    const float* b0 = (const float*)d_in[1];
    const float* w1 = (const float*)d_in[2];
    const float* b1 = (const float*)d_in[3];
    const float* w2 = (const float*)d_in[4];
    const float* b2 = (const float*)d_in[5];
    const float* w3 = (const float*)d_in[6];
    const float* b3 = (const float*)d_in[7];
    const float* w4 = (const float*)d_in[8];
    const float* b4 = (const float*)d_in[9];
    const float* wt = (const float*)d_in[10];
    const float* x  = (const float*)d_in[11];
    float* out = (float*)d_out;

    dim3 grid(NBLK), block(64);
    hipLaunchKernelGGL(phinn_kernel, grid, block, 0, stream,
                       w0, b0, w1, b1, w2, b2, w3, b3, w4, b4, wt, x, out);
}